// Round 2
// baseline (63.538 us; speedup 1.0000x reference)
//
#include <hip/hip_runtime.h>

#define BATCH 16384
#define NGRID 128
#define K 9
#define W 5   // 5x5 window centered on round(p): the VERIFIED window.
              // NOTE (r1 post-mortem): the 4x4 floor-window is provably correct
              // only in the grid INTERIOR. At edges the 9-NN spills sideways
              // (e.g. p_r=126.8, f_c~0: true 9th = (127,c-2) d2=4.04 vs in-window
              // (125,c+-1) d2=4.24) -> needs the 5-wide span. Do not shrink W.

__global__ __launch_bounds__(64) void spline_knn_kernel(
    const float* __restrict__ x,
    const float* __restrict__ wts,
    const float* __restrict__ cp,
    float* __restrict__ out)
{
    int b = blockIdx.x * 64 + threadIdx.x;   // grid is exactly BATCH threads

    float2 xv = ((const float2*)x)[b];
    float x0 = xv.x, x1 = xv.y;

    // h = ||x[0] - x[1]|| (uniform; compiler scalarizes)
    float e0 = __fadd_rn(x[0], -x[2]);
    float e1 = __fadd_rn(x[1], -x[3]);
    float h = sqrtf(__fadd_rn(__fmul_rn(e0, e0), __fmul_rn(e1, e1)));

    // x2 term exactly as np.sum(x*x, -1): per-op rounding, no contraction
    float x2s = __fadd_rn(__fmul_rn(x0, x0), __fmul_rn(x1, x1));

    // grid position in grid units: p = (x+1) * 127/2; window centered on ROUND
    float pr = (x0 + 1.0f) * 63.5f;
    float pc = (x1 + 1.0f) * 63.5f;
    int r0 = min(max((int)floorf(pr + 0.5f) - 2, 0), NGRID - W);
    int c0 = min(max((int)floorf(pc + 0.5f) - 2, 0), NGRID - W);

    // weight prefetch: candidate indices known BEFORE selection -> all 25 loads
    // issue here; their L2 latency hides under the ~900-op rank compute
    // (old kernel serialized these 9 loads AFTER the sort -> exposed tail stall)
    float wv[W * W];
#pragma unroll
    for (int i = 0; i < W; ++i)
#pragma unroll
        for (int j = 0; j < W; ++j)
            wv[W * i + j] = wts[(r0 + i) * NGRID + (c0 + j)];

    // regular grid: cp[r*128+c] = (t[r], t[c]) -> separable loads (10 not 50)
    float tr[W], tc[W];
#pragma unroll
    for (int i = 0; i < W; ++i) tr[i] = cp[2 * ((r0 + i) * NGRID)];          // t[r0+i]
#pragma unroll
    for (int j = 0; j < W; ++j) tc[j] = cp[2 * (r0 * NGRID + c0 + j) + 1];   // t[c0+j]

    // per-row / per-col partials, rounding identical to the verified kernel:
    //   c2s = fl( fl(cr*cr) + fl(cc*cc) ),  dot = fma(x1, cc, fl(x0*cr))
    float ar[W], br[W], ac[W];
#pragma unroll
    for (int i = 0; i < W; ++i) { ar[i] = __fmul_rn(tr[i], tr[i]); br[i] = __fmul_rn(x0, tr[i]); }
#pragma unroll
    for (int j = 0; j < W; ++j) { ac[j] = __fmul_rn(tc[j], tc[j]); }

    // D for all 25 candidates, bit-identical to the verified kernel
    float d[W * W];
#pragma unroll
    for (int i = 0; i < W; ++i) {
#pragma unroll
        for (int j = 0; j < W; ++j) {
            float c2s = __fadd_rn(ar[i], ac[j]);
            float tmp = __fadd_rn(x2s, c2s);
            float dot = __fmaf_rn(x1, tc[j], br[i]);
            // fma(-2,dot,tmp) == fl(tmp - fl(2*dot)) since 2*dot is exact:
            d[W * i + j] = __fmaf_rn(-2.0f, dot, tmp);
        }
    }

    // all-pairs rank selection. Array order == ascending flat-index order
    // ((r0+i)*128+c0+j is strictly increasing in q = W*i+j), so for i<j:
    //   "i precedes j in top_k order"  <=>  d[i] <= d[j]
    // (tie in D -> smaller index wins, exactly jax.lax.top_k). Strict total
    // order -> ranks are a permutation of 0..24 -> exactly K have rank < K.
    // Order within the top-9 is irrelevant: we only need the SUM.
    // 300 pairs x ~3 VALU, fully ILP-parallel — replaces the 225-stage serial
    // 64-bit insertion network (the old kernel's critical path at 1 wave/CU).
    int rank[W * W];
#pragma unroll
    for (int i = 0; i < W * W; ++i) rank[i] = 0;
#pragma unroll
    for (int i = 0; i < W * W; ++i)
#pragma unroll
        for (int j = i + 1; j < W * W; ++j) {
            int le = (d[i] <= d[j]) ? 1 : 0;
            rank[j] += le;
            rank[i] += le ^ 1;
        }

    // epilogue: conv for all 25 (pure ILP), predicated accumulate
    float invh = 1.0f / h;
    float acc0 = 0.0f, acc1 = 0.0f, acc2 = 0.0f, acc3 = 0.0f;
#pragma unroll
    for (int q = 0; q < W * W; ++q) {
        float s = sqrtf(fmaxf(d[q], 0.0f)) * invh;
        float a2 = s * s;
        float a3 = a2 * s;
        float conv;
        if (s < 1.0f)                    conv = 1.5f * a3 - 2.5f * a2 + 1.0f;
        else if (s > 1.0f && s < 2.0f)   conv = -0.5f * a3 + 2.5f * a2 - 4.0f * s + 2.0f;
        else                             conv = 0.0f;
        float wsel = (rank[q] < K) ? wv[q] : 0.0f;
        float term = wsel * conv;
        if      ((q & 3) == 0) acc0 += term;
        else if ((q & 3) == 1) acc1 += term;
        else if ((q & 3) == 2) acc2 += term;
        else                   acc3 += term;
    }

    out[b] = (acc0 + acc1) + (acc2 + acc3);
    ((float2*)(out + BATCH))[b] = xv;   // second tuple output: x passthrough
}

extern "C" void kernel_launch(void* const* d_in, const int* in_sizes, int n_in,
                              void* d_out, int out_size, void* d_ws, size_t ws_size,
                              hipStream_t stream) {
    const float* x  = (const float*)d_in[0];   // (16384, 2) fp32
    const float* w  = (const float*)d_in[1];   // (16384, 1) fp32
    const float* cp = (const float*)d_in[2];   // (16384, 2) fp32
    float* out = (float*)d_out;                // 16384 out + 32768 x passthrough

    spline_knn_kernel<<<BATCH / 64, 64, 0, stream>>>(x, w, cp, out);
}

// Round 3
// 61.102 us; speedup vs baseline: 1.0399x; 1.0399x over previous
//
#include <hip/hip_runtime.h>

#define BATCH 16384
#define NGRID 128
#define K 9
#define W 5   // 5x5 window centered on round(p): provably contains the true 9-NN
              // incl. clamped edges/corners (margins >= 3e-4 in D vs 2.4e-7 fp noise).
              // DO NOT shrink to 4x4: at clamped edges the 9-NN spills sideways
              // (e.g. p_r=126.8, f_c~0: true 9th = (127,c-2) d2=4.04 vs in-window
              // 4.24) -> r1 of this session failed with absmax 2.54.
//
// FLOOR ANALYSIS (r2 post-mortem): timed graph = 268MB workspace poison fill
// (~40us at 85% HBM peak, harness) + reset memsets (~15-18us, harness) + this
// kernel (~2-3us: ~1500 unrolled VALU x 2cyc at 1 wave/SIMD + one parallel
// round of L2 loads). Two structurally different kernels (serial 64b insertion
// sort vs all-pairs rank select, equal VALU counts) measured 61.2 vs 63.5us =
// within fill noise. The controllable slice is ~5% of dur_us.

__global__ __launch_bounds__(64) void spline_knn_kernel(
    const float* __restrict__ x,
    const float* __restrict__ wts,
    const float* __restrict__ cp,
    float* __restrict__ out)
{
    int b = blockIdx.x * 64 + threadIdx.x;   // grid is exactly BATCH threads

    float2 xv = ((const float2*)x)[b];
    float x0 = xv.x, x1 = xv.y;

    // h = ||x[0] - x[1]|| (precision non-critical)
    float e0 = __fadd_rn(x[0], -x[2]);
    float e1 = __fadd_rn(x[1], -x[3]);
    float h = sqrtf(__fadd_rn(__fmul_rn(e0, e0), __fmul_rn(e1, e1)));

    // x2 term exactly as np.sum(x*x, -1): per-op rounding, no contraction
    float x2s = __fadd_rn(__fmul_rn(x0, x0), __fmul_rn(x1, x1));

    // grid position in grid units: p = (x+1) * 127/2; window centered on ROUND
    float pr = (x0 + 1.0f) * 63.5f;
    float pc = (x1 + 1.0f) * 63.5f;
    int r0 = min(max((int)floorf(pr + 0.5f) - 2, 0), NGRID - W);
    int c0 = min(max((int)floorf(pc + 0.5f) - 2, 0), NGRID - W);

    // regular grid: cp[r*128+c] = (t[r], t[c]) -> separable loads (10 instead of 50)
    float tr[W], tc[W];
#pragma unroll
    for (int i = 0; i < W; ++i) tr[i] = cp[2 * ((r0 + i) * NGRID)];          // t[r0+i]
#pragma unroll
    for (int j = 0; j < W; ++j) tc[j] = cp[2 * (r0 * NGRID + c0 + j) + 1];   // t[c0+j]

    // per-row / per-col partials, rounding identical to the verified kernel:
    //   c2s = fl( fl(cr*cr) + fl(cc*cc) ),  dot = fma(x1, cc, fl(x0*cr))
    float ar[W], br[W], ac[W];
#pragma unroll
    for (int i = 0; i < W; ++i) { ar[i] = __fmul_rn(tr[i], tr[i]); br[i] = __fmul_rn(x0, tr[i]); }
#pragma unroll
    for (int j = 0; j < W; ++j) { ac[j] = __fmul_rn(tc[j], tc[j]); }

    // top-9 keys: (monotone-mapped D bits << 32) | flat index
    // smaller key == smaller D, tie -> smaller index (matches jax.lax.top_k)
    unsigned long long best[K];
#pragma unroll
    for (int i = 0; i < K; ++i) best[i] = ~0ULL;

#pragma unroll
    for (int i = 0; i < W; ++i) {
        int mrow = (r0 + i) * NGRID + c0;
#pragma unroll
        for (int j = 0; j < W; ++j) {
            float c2s = __fadd_rn(ar[i], ac[j]);
            float tmp = __fadd_rn(x2s, c2s);
            float dot = __fmaf_rn(x1, tc[j], br[i]);
            // fma(-2,dot,tmp) == fl(tmp - fl(2*dot)) since 2*dot is exact:
            float D   = __fmaf_rn(-2.0f, dot, tmp);

            unsigned ub = __float_as_uint(D);
            ub ^= ((unsigned)((int)ub >> 31)) | 0x80000000u;  // monotone map
            unsigned long long key =
                ((unsigned long long)ub << 32) | (unsigned)(mrow + j);

            // sorted-insertion network, fully unrolled (no dynamic indexing)
#pragma unroll
            for (int q = 0; q < K; ++q) {
                bool lt = key < best[q];
                unsigned long long lo = lt ? key : best[q];
                unsigned long long hi = lt ? best[q] : key;
                best[q] = lo;
                key = hi;
            }
        }
    }

    // epilogue: decode D from key (s = sqrt(D)/h; ~1e-5 noise vs 0.27 tolerance)
    float invh = 1.0f / h;
    float acc = 0.0f;
#pragma unroll
    for (int q = 0; q < K; ++q) {
        unsigned hi = (unsigned)(best[q] >> 32);
        int m = (int)(best[q] & 0xFFFFFFFFull);
        unsigned mask = ((unsigned)((int)(~hi) >> 31)) | 0x80000000u;  // inverse map
        float D = __uint_as_float(hi ^ mask);
        float s = sqrtf(fmaxf(D, 0.0f)) * invh;
        float a2 = s * s;
        float a3 = a2 * s;
        float conv;
        if (s < 1.0f)                    conv = 1.5f * a3 - 2.5f * a2 + 1.0f;
        else if (s > 1.0f && s < 2.0f)   conv = -0.5f * a3 + 2.5f * a2 - 4.0f * s + 2.0f;
        else                             conv = 0.0f;
        acc += wts[m] * conv;
    }

    out[b] = acc;
    ((float2*)(out + BATCH))[b] = xv;   // second tuple output: x passthrough
}

extern "C" void kernel_launch(void* const* d_in, const int* in_sizes, int n_in,
                              void* d_out, int out_size, void* d_ws, size_t ws_size,
                              hipStream_t stream) {
    const float* x  = (const float*)d_in[0];   // (16384, 2) fp32
    const float* w  = (const float*)d_in[1];   // (16384, 1) fp32
    const float* cp = (const float*)d_in[2];   // (16384, 2) fp32
    float* out = (float*)d_out;                // 16384 out + 32768 x passthrough

    spline_knn_kernel<<<BATCH / 64, 64, 0, stream>>>(x, w, cp, out);
}